// Round 15
// baseline (220.711 us; speedup 1.0000x reference)
//
#include <hip/hip_runtime.h>
#include <math.h>

typedef __bf16 bf16x8 __attribute__((ext_vector_type(8)));
typedef float f32x4 __attribute__((ext_vector_type(4)));

// ---------- helpers ----------

__device__ __forceinline__ unsigned short f2bf(float f) {
    unsigned int u = __float_as_uint(f);
    u += 0x7FFFu + ((u >> 16) & 1u);   // round-to-nearest-even
    return (unsigned short)(u >> 16);
}

// fast logcosh via HW v_exp/v_log (TRANS pipe). abs err ~1e-6/elem, budget 0.02.
__device__ __forceinline__ float logcosh_fast(float v) {
    float a = fabsf(v);
    float t = __expf(-2.0f * a);
    return a + (__logf(1.0f + t) - 0.6931471805599453f);
}

// DPP row_shr add; after shr 1,2,4,8 lane 15 of each 16-lane row holds row sum.
template <int CTRL>
__device__ __forceinline__ float dppadd(float x) {
    int y = __builtin_amdgcn_update_dpp(0, __float_as_int(x), CTRL, 0xf, 0xf, true);
    return x + __int_as_float(y);
}

__device__ __forceinline__ void gload_lds16(const void* g, void* l) {
    __builtin_amdgcn_global_load_lds(
        (__attribute__((address_space(1))) void*)(void*)g,
        (__attribute__((address_space(3))) void*)l, 16, 0, 0);
}

#define SBAR()  __builtin_amdgcn_s_barrier()
#define SCHED() __builtin_amdgcn_sched_barrier(0)

// ---------- kernel 1: invert permutations ----------
__global__ __launch_bounds__(256) void k_invert(const int* __restrict__ perms,
                                                int* __restrict__ inv) {
    int t = blockIdx.x * 256 + threadIdx.x;
    int g = t >> 10, n = t & 1023;
    inv[(g << 10) + perms[t]] = n;
}

// ---------- kernel 2: bT[j][k] = bf16(W[inv[g][k]][f]), j = g*16+f ----------
__global__ __launch_bounds__(256) void k_build_bt(const float* __restrict__ W,
                                                  const int* __restrict__ inv,
                                                  unsigned short* __restrict__ bT) {
    int j = blockIdx.x;
    int g = j >> 4, f = j & 15;
    const int* invg = inv + (g << 10);
    size_t rowbase = (size_t)j << 10;
#pragma unroll
    for (int i = 0; i < 4; ++i) {
        int k = (i << 8) + threadIdx.x;
        int n = invg[k];
        bT[rowbase + k] = f2bf(W[(n << 4) + f]);
    }
}

// ---------- kernel 3: x -> bf16, out[row] = v_bias * sum(x[row]) ----------
__global__ __launch_bounds__(256) void k_convert(const float* __restrict__ x,
                                                 const float* __restrict__ vb,
                                                 unsigned short* __restrict__ xb,
                                                 float* __restrict__ out) {
    int row = blockIdx.x, tid = threadIdx.x;
    size_t base = ((size_t)row << 10) + (tid << 2);
    float4 v = *reinterpret_cast<const float4*>(x + base);
    ushort4 h;
    h.x = f2bf(v.x); h.y = f2bf(v.y); h.z = f2bf(v.z); h.w = f2bf(v.w);
    *reinterpret_cast<ushort4*>(xb + base) = h;
    float s = v.x + v.y + v.z + v.w;
#pragma unroll
    for (int off = 32; off > 0; off >>= 1) s += __shfl_down(s, off);
    __shared__ float ls[4];
    if ((tid & 63) == 0) ls[tid >> 6] = s;
    __syncthreads();
    if (tid == 0) out[row] = vb[0] * (ls[0] + ls[1] + ls[2] + ls[3]);
}

// ---------- kernel 4: 256x256 GEMM, FAT-WAVE: 4 waves, 128x128 out per wave ----
// 1 wave/SIMD owns its MFMA pipe; LDS frag reads drop 192->128 per tile per CU
// (per-wave frag bytes (128+128)x64x2B = 32KB vs 24KB x 8 waves before).
// acc[8][8] f32x4 = 256 AGPR + aF/bF 128 VGPR < 512 cap at 1 wave/SIMD.
// Per tile (one barrier, stage-at-front = R14):
//   front: stage A/B(t+1) -> other buf (16 gload_lds, WAR-free);
//          reads: bF[0..7] (16) + aF[0],aF[1] (4)
//   m=0..5: { issue aF[m+2] (2); lgkm(4) -> aF[m] ready; 16 MFMA }
//   m=6: lgkm(2); m=7: lgkm(0); 16 MFMA each
//   end: vmcnt(0); SBAR (4 waves, cheap)

#define MFMA_M(MM)                                                               \
    _Pragma("unroll") for (int k_ = 0; k_ < 2; ++k_)                             \
    _Pragma("unroll") for (int n_ = 0; n_ < 8; ++n_)                             \
        acc[MM][n_] = __builtin_amdgcn_mfma_f32_16x16x32_bf16(                   \
            aF[MM][k_], bF[n_][k_], acc[MM][n_], 0, 0, 0);

// stage instr i (of 8) for one 256x64 tile: 2048 chunks of 16B, 256 threads
__device__ __forceinline__ void stage8(unsigned short* dst, const unsigned short* src,
                                       int voff, int i, int wv) {
    gload_lds16(src + voff, dst + (((i << 8) + (wv << 6)) << 3));
}

template <bool ST, int VM>
__device__ __forceinline__ void tile_fat(
    const unsigned short* Ap, const unsigned short* Bp,   // read bufs (tile t)
    unsigned short* AsD, unsigned short* BsD,             // other bufs (t+1 dst)
    const unsigned short* xsrc, const unsigned short* bsrc,
    f32x4 (&acc)[8][8], const int (&vs)[8],
    int aRow, int bRow, int po0, int po1, int wv) {
    bf16x8 aF[8][2], bF[8][2];

    // front: stage t+1 into the other buffers (WAR-free), then 20 ds_reads
    if (ST) {
#pragma unroll
        for (int i = 0; i < 8; ++i) stage8(AsD, xsrc, vs[i], i, wv);
#pragma unroll
        for (int i = 0; i < 8; ++i) stage8(BsD, bsrc, vs[i], i, wv);
    }
    SCHED();
#pragma unroll
    for (int n = 0; n < 8; ++n) {
        bF[n][0] = *reinterpret_cast<const bf16x8*>(Bp + bRow + po0 + n * 1024);
        bF[n][1] = *reinterpret_cast<const bf16x8*>(Bp + bRow + po1 + n * 1024);
    }
#pragma unroll
    for (int m = 0; m < 2; ++m) {
        aF[m][0] = *reinterpret_cast<const bf16x8*>(Ap + aRow + po0 + m * 1024);
        aF[m][1] = *reinterpret_cast<const bf16x8*>(Ap + aRow + po1 + m * 1024);
    }
    SCHED();

    // m=0..5: prefetch aF[m+2], counted lgkm(4), 16 MFMA
#pragma unroll
    for (int m = 0; m < 6; ++m) {
        aF[m + 2][0] = *reinterpret_cast<const bf16x8*>(Ap + aRow + po0 + (m + 2) * 1024);
        aF[m + 2][1] = *reinterpret_cast<const bf16x8*>(Ap + aRow + po1 + (m + 2) * 1024);
        SCHED();
        asm volatile("s_waitcnt lgkmcnt(4)" ::: "memory");
        SCHED();
        __builtin_amdgcn_s_setprio(1);
        MFMA_M(m)
        __builtin_amdgcn_s_setprio(0);
        SCHED();
    }
    // m=6: aF[6] ready at lgkm(2)
    asm volatile("s_waitcnt lgkmcnt(2)" ::: "memory");
    SCHED();
    __builtin_amdgcn_s_setprio(1);
    MFMA_M(6)
    __builtin_amdgcn_s_setprio(0);
    SCHED();
    // m=7: aF[7] ready at lgkm(0)
    asm volatile("s_waitcnt lgkmcnt(0)" ::: "memory");
    SCHED();
    __builtin_amdgcn_s_setprio(1);
    MFMA_M(7)
    __builtin_amdgcn_s_setprio(0);
    SCHED();
    if (VM == 0) { asm volatile("s_waitcnt vmcnt(0)" ::: "memory"); }
    SCHED();
    SBAR();
}

__global__ __launch_bounds__(256, 1) void k_gemm(const unsigned short* __restrict__ xb,
                                                 const unsigned short* __restrict__ bT,
                                                 const float* __restrict__ bias,
                                                 float* __restrict__ partial, int B) {
    __shared__ unsigned short As[2][256 * 64];
    __shared__ unsigned short Bs[2][256 * 64];

    const int tid = threadIdx.x;
    const int lane = tid & 63;
    const int wv = tid >> 6;           // 0..3
    const int wm = wv >> 1;            // 0..1  (M half)
    const int wn = wv & 1;             // 0..1  (N half)
    const int lr = lane & 15;
    const int lk = lane >> 4;

    // XCD-bijective swizzle (nwg = 1024, % 8 == 0)
    const int fid = blockIdx.y * gridDim.x + blockIdx.x;
    const int cpx = (gridDim.x * gridDim.y) >> 3;
    const int swz = (fid & 7) * cpx + (fid >> 3);
    const int cbx = swz & 15;          // col block (0..15)
    const int row0 = (swz >> 4) << 8;  // row block * 256
    const int j0 = cbx << 8;

    const unsigned short* xbase = xb + ((size_t)row0 << 10);
    const unsigned short* bbase = bT + ((size_t)j0 << 10);

    // per-wave LDS read bases (short units); +m*1024 / +n*1024 imm offsets
    const int aRow = (wm * 128 + lr) * 64;
    const int bRow = (wn * 128 + lr) * 64;
    const int po0 = (lk ^ (lr & 7)) * 8;
    const int po1 = ((4 + lk) ^ (lr & 7)) * 8;

    // per-thread stage source voffsets (shorts); instr i covers chunks i*256+tid
    int vs[8];
#pragma unroll
    for (int i = 0; i < 8; ++i) {
        int cc = (i << 8) + tid;
        int r = cc >> 3;
        int cs = (cc & 7) ^ (r & 7);
        vs[i] = (r << 10) + (cs << 3);
    }

    f32x4 acc[8][8];
#pragma unroll
    for (int m = 0; m < 8; ++m)
#pragma unroll
        for (int n = 0; n < 8; ++n)
            acc[m][n] = {0.f, 0.f, 0.f, 0.f};

    // ---- prologue: stage tile0(A,B) + tile1(A,B); wait tile0; SBAR ----
#pragma unroll
    for (int i = 0; i < 8; ++i) stage8(&As[0][0], xbase, vs[i], i, wv);
#pragma unroll
    for (int i = 0; i < 8; ++i) stage8(&Bs[0][0], bbase, vs[i], i, wv);
#pragma unroll
    for (int i = 0; i < 8; ++i) stage8(&As[1][0], xbase + 64, vs[i], i, wv);
#pragma unroll
    for (int i = 0; i < 8; ++i) stage8(&Bs[1][0], bbase + 64, vs[i], i, wv);
    asm volatile("s_waitcnt vmcnt(16)" ::: "memory");   // tile0's 16 landed
    SCHED();
    SBAR();

    // ---- t=0: tile1 already prestaged (in flight; drained by t0-end vmcnt(0))
    tile_fat<false, 0>(&As[0][0], &Bs[0][0], &As[1][0], &Bs[1][0],
                       xbase, bbase, acc, vs, aRow, bRow, po0, po1, wv);
    // ---- t=1..14: front-stage t+1 into the other buffers ----
    for (int tt = 0; tt < 7; ++tt) {
        const int t = 2 * tt + 1;   // odd tile: read buf1, stage t+1 -> buf0
        tile_fat<true, 0>(&As[1][0], &Bs[1][0], &As[0][0], &Bs[0][0],
                          xbase + ((t + 1) << 6), bbase + ((t + 1) << 6),
                          acc, vs, aRow, bRow, po0, po1, wv);
        // even tile t+1: read buf0, stage t+2 -> buf1
        tile_fat<true, 0>(&As[0][0], &Bs[0][0], &As[1][0], &Bs[1][0],
                          xbase + ((t + 2) << 6), bbase + ((t + 2) << 6),
                          acc, vs, aRow, bRow, po0, po1, wv);
    }
    // ---- t=15: nothing to stage or wait on ----
    tile_fat<false, -1>(&As[1][0], &Bs[1][0], &As[0][0], &Bs[0][0],
                        xbase, bbase, acc, vs, aRow, bRow, po0, po1, wv);

    // ---- epilogue: logcosh + in-reg n-sum + DPP row-reduce; LDS combine ----
    float* rowsum = (float*)&As[0][0];   // [2][256]
    const float bv = bias[lr];           // C col % 16 == lane&15
#pragma unroll
    for (int m = 0; m < 8; ++m) {
#pragma unroll
        for (int r = 0; r < 4; ++r) {
            float s = 0.f;
#pragma unroll
            for (int n = 0; n < 8; ++n) s += logcosh_fast(acc[m][n][r] + bv);
            s = dppadd<0x111>(s);
            s = dppadd<0x112>(s);
            s = dppadd<0x114>(s);
            s = dppadd<0x118>(s);
            if (lr == 15)
                rowsum[wn * 256 + wm * 128 + m * 16 + lk * 4 + r] = s;
        }
    }
    __syncthreads();
    if (tid < 256) {
        float s = rowsum[tid] + rowsum[256 + tid];
        partial[(size_t)cbx * B + row0 + tid] = s;
    }
}

// ---------- kernel 5: out[b] += sum_cb partial[cb][b] ----------
__global__ __launch_bounds__(256) void k_final(const float* __restrict__ partial,
                                               float* __restrict__ out, int ncb, int B) {
    int b = blockIdx.x * 256 + threadIdx.x;
    float s = out[b];
    for (int c = 0; c < ncb; ++c) s += partial[(size_t)c * B + b];
    out[b] = s;
}

// ---------- launch ----------
extern "C" void kernel_launch(void* const* d_in, const int* in_sizes, int n_in,
                              void* d_out, int out_size, void* d_ws, size_t ws_size,
                              hipStream_t stream) {
    const float* x      = (const float*)d_in[0];  // [B,1024]
    const float* W      = (const float*)d_in[1];  // [1024,16]
    const float* bias   = (const float*)d_in[2];  // [16]
    const float* v_bias = (const float*)d_in[3];  // [1]
    const int*   perms  = (const int*)d_in[4];    // [G,1024]
    float* out = (float*)d_out;

    const int N  = 1024;
    const int B  = in_sizes[0] / N;   // 16384
    const int G  = in_sizes[4] / N;   // 256
    const int GF = G * 16;            // 4096
    const int NCB = GF / 256;         // 16 col blocks

    char* w = (char*)d_ws;
    unsigned short* xb = (unsigned short*)w;                           // B*N*2   = 32 MB
    unsigned short* bT = (unsigned short*)(w + (size_t)B * N * 2);     // GF*N*2  = 8 MB
    int* inv = (int*)(w + (size_t)B * N * 2 + (size_t)GF * N * 2);     // G*N*4   = 1 MB
    float* partial = (float*)(w + (size_t)B * N * 2 + (size_t)GF * N * 2
                              + (size_t)G * N * 4);                    // NCB*B*4 = 1 MB

    k_invert<<<G * N / 256, 256, 0, stream>>>(perms, inv);
    k_build_bt<<<GF, 256, 0, stream>>>(W, inv, bT);
    k_convert<<<B, 256, 0, stream>>>(x, v_bias, xb, out);
    k_gemm<<<dim3(NCB, B / 256), 256, 0, stream>>>(xb, bT, bias, partial, B);
    k_final<<<B / 256, 256, 0, stream>>>(partial, out, NCB, B);
}